// Round 5
// baseline (448.903 us; speedup 1.0000x reference)
//
#include <hip/hip_runtime.h>

#define NN 50000
#define DD 128
#define EE 800000
#define SLOTS 64          // max degree cap (Poisson(16): P(deg>=65) ~ 1e-20/node)
#define CSTRIDE 16        // ints per counter -> one counter per 64B line
#define NSHARD 8          // XCDs; blockIdx % 8 ~ XCD round-robin (perf heuristic only)
#define SHARD_NODES (NN / NSHARD)   // 6250

// merged prep+bucket block ranges (bucket first: it's the long pole)
#define BKT_BLKS  6256    // 782 chunks x 8 shards
#define CVT_BLKS  6250    // NN*DD/4 float4s / 256
#define WCAT_BLKS 384
#define ZR_BLKS   1

// zero pass: cntpad (200000 uint4) + eidx sentinel fill (400000 uint4)
#define ZCNT_U4   (NN * CSTRIDE / 4)
#define ZEIDX_U4  (NN * SLOTS / 8)
#define ZR_GRID   ((ZCNT_U4 + ZEIDX_U4 + 255) / 256)

typedef short bf16x8 __attribute__((ext_vector_type(8)));   // 8 bf16 = 4 VGPRs
typedef float f32x4  __attribute__((ext_vector_type(4)));
typedef unsigned u32x4 __attribute__((ext_vector_type(4))); // asm payload quad (4 VGPRs)

// ---- bf16 helpers (RNE) ----
__device__ __forceinline__ unsigned short f2bf(float f) {
    union { float f; unsigned u; } c; c.f = f;
    unsigned r = c.u + 0x7fffu + ((c.u >> 16) & 1u);
    return (unsigned short)(r >> 16);
}
__device__ __forceinline__ float bflo(unsigned p) { union { unsigned u; float f; } c; c.u = p << 16; return c.f; }
__device__ __forceinline__ float bfhi(unsigned p) { union { unsigned u; float f; } c; c.u = p & 0xffff0000u; return c.f; }
__device__ __forceinline__ unsigned packbf(float a, float b) { return (unsigned)f2bf(a) | ((unsigned)f2bf(b) << 16); }

// ---------------- cnt zero + eidx sentinel fill (must precede bucket atomics) ----------------
// eidx prefilled with NN (0xC350) so slots >= deg point at the zero sentinel row: the gather
// then needs NO cap-masking, every round is safe to load, and addresses don't depend on deg.
__global__ __launch_bounds__(256) void zero_kernel(int* __restrict__ cntpad, unsigned short* __restrict__ eidx) {
    int i = blockIdx.x * 256 + threadIdx.x;     // uint4 index
    if (i < ZCNT_U4) {
        ((uint4*)cntpad)[i] = make_uint4(0, 0, 0, 0);
    } else {
        int j = i - ZCNT_U4;
        if (j < ZEIDX_U4) ((uint4*)eidx)[j] = make_uint4(0xC350C350u, 0xC350C350u, 0xC350C350u, 0xC350C350u);
    }
}

// ---------------- merged prep + padded-slot CSR build (independent parts, one dispatch) ----
// R11 evidence: bucket (~40us) + prep (~25us) merged costs only ~45us (overlapped).
__global__ __launch_bounds__(256) void prepbucket_kernel(const int* __restrict__ src, const int* __restrict__ dst,
                                                         const float* __restrict__ x,
                                                         const float* __restrict__ W1l, const float* __restrict__ W1r,
                                                         const float* __restrict__ W2l, const float* __restrict__ W2r,
                                                         const float* __restrict__ W3l, const float* __restrict__ W3r,
                                                         int* __restrict__ cntpad, unsigned short* __restrict__ eidx,
                                                         unsigned short* __restrict__ xb,
                                                         unsigned short* __restrict__ Bw,
                                                         unsigned short* __restrict__ h1b,
                                                         unsigned short* __restrict__ h2b) {
    const int b = blockIdx.x;
    const int t = threadIdx.x;
    if (b < BKT_BLKS) {
        const int shard = b & (NSHARD - 1);
        const int chunk = b >> 3;
        const int lo = shard * SHARD_NODES;
        const int hi = lo + SHARD_NODES;
        int i = (chunk * 256 + t) * 4;
        if (i + 3 < EE) {
            int4 dv = *(const int4*)(dst + i);
            int4 sv = *(const int4*)(src + i);
            if (dv.x >= lo && dv.x < hi) { int p = atomicAdd(&cntpad[dv.x * CSTRIDE], 1); if (p < SLOTS) eidx[dv.x * SLOTS + p] = (unsigned short)sv.x; }
            if (dv.y >= lo && dv.y < hi) { int p = atomicAdd(&cntpad[dv.y * CSTRIDE], 1); if (p < SLOTS) eidx[dv.y * SLOTS + p] = (unsigned short)sv.y; }
            if (dv.z >= lo && dv.z < hi) { int p = atomicAdd(&cntpad[dv.z * CSTRIDE], 1); if (p < SLOTS) eidx[dv.z * SLOTS + p] = (unsigned short)sv.z; }
            if (dv.w >= lo && dv.w < hi) { int p = atomicAdd(&cntpad[dv.w * CSTRIDE], 1); if (p < SLOTS) eidx[dv.w * SLOTS + p] = (unsigned short)sv.w; }
        } else {
            for (int e = i; e < EE; ++e) {
                int d = dst[e];
                if (d >= lo && d < hi) {
                    int p = atomicAdd(&cntpad[d * CSTRIDE], 1);
                    if (p < SLOTS) eidx[d * SLOTS + p] = (unsigned short)src[e];
                }
            }
        }
    } else if (b < BKT_BLKS + CVT_BLKS) {
        int i = (b - BKT_BLKS) * 256 + t;         // float4 index, exactly NN*DD/4
        float4 v = ((const float4*)x)[i];
        uint2 o;
        o.x = packbf(v.x, v.y);
        o.y = packbf(v.z, v.w);
        ((uint2*)xb)[i] = o;
    } else if (b < BKT_BLKS + CVT_BLKS + WCAT_BLKS) {
        int gid = (b - BKT_BLKS - CVT_BLKS) * 256 + t;   // 0..98303
        int layer = gid >> 15;
        int rem = gid & 32767;
        int c = rem >> 8;
        int k = rem & 255;
        const float* Wl = (layer == 0) ? W1l : (layer == 1) ? W2l : W3l;
        const float* Wr = (layer == 0) ? W1r : (layer == 1) ? W2r : W3r;
        float v = (k < 128) ? Wl[(size_t)c * DD + k] : Wr[(size_t)c * DD + (k - 128)];
        Bw[gid] = f2bf(v);
    } else {
        // zero sentinel row NN of xb/h1b/h2b: 3 rows x 256B = 48 uint4
        if (t < 48) {
            unsigned short* base = (t < 16) ? xb : (t < 32) ? h1b : h2b;
            ((uint4*)(base + (size_t)NN * DD))[t & 15] = make_uint4(0, 0, 0, 0);
        }
    }
}

// ---------------- fused layer: gather 16 nodes -> LDS, then MFMA dual-GEMM ----------------
// R13/R14/R15 post-mortems: every compiler-visible register pipeline was defeated --
// demoted to scratch (R13: lambdas), sunk to use (R14: VGPR stayed 32), or spilled (R15:
// demand ~90 > (256,6)'s 85-reg cap; WRITE_SIZE 154 MB of spill traffic).
// R16: make the payload CONTRACTUAL. Loads are inline-asm global_load_dwordx4 with "=v"
// u32x4 outputs (asm outputs must be VGPRs), 32-bit voffset + SGPR base (1 addr reg/load).
// Hand-counted s_waitcnt vmcnt(4) (depth-2: 8 outstanding, wait oldest 4 = stage A) +
// sched_barrier(0) after each wait (rule #18: compiler hoists VALU past inline-asm waits).
// Final vmcnt(0) drain before any register reuse (last iteration's dead outputs would
// otherwise be clobbered in flight). Demand ~55 VGPR < 64 cap at (256,8) -> 32 waves/CU;
// NO compiler VMEM inside the loop (a spill-reload would corrupt the manual counting --
// WRITE_SIZE is the tripwire). Sustained 8 loads/wave vs baseline's bursty 16-then-drain.
template <int RELU, int WRITE_F32>
__global__ __launch_bounds__(256, 8) void layer_kernel(const unsigned short* __restrict__ hb,
                                                       const unsigned short* __restrict__ eidx,
                                                       const int* __restrict__ cntpad,
                                                       const unsigned short* __restrict__ Bw,
                                                       const float* __restrict__ bias,
                                                       float* __restrict__ outf,
                                                       unsigned short* __restrict__ outb, int n) {
    (void)n;
    __shared__ __align__(16) unsigned short sA[16][136];
    const int tid  = threadIdx.x;
    const int w    = tid >> 6;          // wave 0..3
    const int lane = tid & 63;
    const int row0 = blockIdx.x * 16;
    const int sub  = lane >> 4;         // quarter 0..3 -> node within wave
    const int q    = lane & 15;         // 16B slot within the 256B row
    const unsigned q16 = (unsigned)(q * 16);

    // ---- Phase A: 4 nodes per wave, one per quarter; lane q owns channels 8q..8q+7 ----
    const int node = row0 + (w << 2) + sub;
    const int deg  = cntpad[node * CSTRIDE];
    // lane's 4 slot indices (slots q*4..q*4+3 of its node); sentinel-padded past deg
    uint2 mi = *(const uint2*)(eidx + (size_t)node * SLOTS + q * 4);

    const int cap = deg < SLOTS ? deg : SLOTS;
    int cmax = cap;
    cmax = max(cmax, __shfl_xor(cmax, 16));
    cmax = max(cmax, __shfl_xor(cmax, 32));
    const int rounds  = (cmax + 3) >> 2;            // wave-uniform, 0..16
    const int rounds2 = (rounds + 1) & ~1;          // pad to x2; pad rounds hit sentinel

    float a0 = 0.f, a1 = 0.f, a2 = 0.f, a3 = 0.f, a4 = 0.f, a5 = 0.f, a6 = 0.f, a7 = 0.f;

// round RR: source lane (sub<<4)|(RR&15) holds slots 4RR..4RR+3; RR>=16 -> sentinel row.
// voffset = idx*256 + q*16 (bytes, < 2^24); base hb stays in an SGPR pair.
#define GLOADA(RR, V0, V1, V2, V3)                                            \
    {                                                                         \
        const int rr_ = (RR);                                                 \
        const int sl_ = (sub << 4) | (rr_ & 15);                              \
        unsigned p0_ = (unsigned)__shfl((int)mi.x, sl_);                      \
        unsigned p1_ = (unsigned)__shfl((int)mi.y, sl_);                      \
        p0_ = (rr_ < 16) ? p0_ : 0xC350C350u;                                 \
        p1_ = (rr_ < 16) ? p1_ : 0xC350C350u;                                 \
        unsigned o0_ = ((p0_ & 0xffffu) << 8) + q16;                          \
        unsigned o1_ = ((p0_ >> 16) << 8) + q16;                              \
        unsigned o2_ = ((p1_ & 0xffffu) << 8) + q16;                          \
        unsigned o3_ = ((p1_ >> 16) << 8) + q16;                              \
        asm volatile("global_load_dwordx4 %0, %1, %2" : "=v"(V0) : "v"(o0_), "s"(hb) : "memory"); \
        asm volatile("global_load_dwordx4 %0, %1, %2" : "=v"(V1) : "v"(o1_), "s"(hb) : "memory"); \
        asm volatile("global_load_dwordx4 %0, %1, %2" : "=v"(V2) : "v"(o2_), "s"(hb) : "memory"); \
        asm volatile("global_load_dwordx4 %0, %1, %2" : "=v"(V3) : "v"(o3_), "s"(hb) : "memory"); \
    }

#define ACCUM(V0, V1, V2, V3)                                                 \
    {                                                                         \
        a0 += (bflo(V0[0]) + bflo(V1[0])) + (bflo(V2[0]) + bflo(V3[0]));      \
        a1 += (bfhi(V0[0]) + bfhi(V1[0])) + (bfhi(V2[0]) + bfhi(V3[0]));      \
        a2 += (bflo(V0[1]) + bflo(V1[1])) + (bflo(V2[1]) + bflo(V3[1]));      \
        a3 += (bfhi(V0[1]) + bfhi(V1[1])) + (bfhi(V2[1]) + bfhi(V3[1]));      \
        a4 += (bflo(V0[2]) + bflo(V1[2])) + (bflo(V2[2]) + bflo(V3[2]));      \
        a5 += (bfhi(V0[2]) + bfhi(V1[2])) + (bfhi(V2[2]) + bfhi(V3[2]));      \
        a6 += (bflo(V0[3]) + bflo(V1[3])) + (bflo(V2[3]) + bflo(V3[3]));      \
        a7 += (bfhi(V0[3]) + bfhi(V1[3])) + (bfhi(V2[3]) + bfhi(V3[3]));      \
    }

    u32x4 A0, A1, A2, A3, B0, B1, B2, B3;
    GLOADA(0, A0, A1, A2, A3);                      // depth-2 prologue: 8 loads in flight
    GLOADA(1, B0, B1, B2, B3);
#pragma unroll 1
    for (int r = 0; r < rounds2; r += 2) {
        asm volatile("s_waitcnt vmcnt(4)" ::: "memory");   // stage A's 4 loads returned
        __builtin_amdgcn_sched_barrier(0);
        ACCUM(A0, A1, A2, A3);
        __builtin_amdgcn_sched_barrier(0);
        GLOADA(r + 2, A0, A1, A2, A3);
        asm volatile("s_waitcnt vmcnt(4)" ::: "memory");   // stage B's 4 loads returned
        __builtin_amdgcn_sched_barrier(0);
        ACCUM(B0, B1, B2, B3);
        __builtin_amdgcn_sched_barrier(0);
        GLOADA(r + 3, B0, B1, B2, B3);
    }
    asm volatile("s_waitcnt vmcnt(0)" ::: "memory");       // drain dead in-flight loads
    __builtin_amdgcn_sched_barrier(0);                     // before regs get reused
#undef GLOADA
#undef ACCUM

    {
        const float inv = (deg > 0) ? (1.0f / (float)deg) : 0.f;
        uint4 o;
        o.x = packbf(a0 * inv, a1 * inv);
        o.y = packbf(a2 * inv, a3 * inv);
        o.z = packbf(a4 * inv, a5 * inv);
        o.w = packbf(a6 * inv, a7 * inv);
        *(uint4*)&sA[(w << 2) | sub][q * 8] = o;
    }
    __syncthreads();

    // ---- Phase B: MFMA dual-GEMM. All waves share the 16 rows; wave w owns 32 cols ----
    const int m    = lane & 15;
    const int quad = lane >> 4;
    const int arow = row0 + m;

    f32x4 acc[2];
    acc[0] = (f32x4){0.f, 0.f, 0.f, 0.f};
    acc[1] = (f32x4){0.f, 0.f, 0.f, 0.f};

    const unsigned short* aptr = hb + (size_t)arow * DD + quad * 8;
#pragma unroll
    for (int ph = 0; ph < 2; ++ph) {
#pragma unroll
        for (int ks = 0; ks < 4; ++ks) {
            bf16x8 af;
            if (ph == 0) {
                af = *(const bf16x8*)&sA[m][ks * 32 + quad * 8];
            } else {
                af = *(const bf16x8*)(aptr + ks * 32);
            }
            const int koff = ph * 128 + ks * 32 + quad * 8;
#pragma unroll
            for (int ct = 0; ct < 2; ++ct) {
                const int c = w * 32 + ct * 16 + m;
                bf16x8 bfv = *(const bf16x8*)(Bw + (size_t)c * 256 + koff);
                acc[ct] = __builtin_amdgcn_mfma_f32_16x16x32_bf16(af, bfv, acc[ct], 0, 0, 0);
            }
        }
    }

#pragma unroll
    for (int ct = 0; ct < 2; ++ct) {
        const int gcol = w * 32 + ct * 16 + m;
        const float bv = bias[gcol];
#pragma unroll
        for (int r = 0; r < 4; ++r) {
            const int grow = row0 + quad * 4 + r;
            float v = acc[ct][r] + bv;
            if (RELU) v = fmaxf(v, 0.f);
            if (WRITE_F32) outf[(size_t)grow * DD + gcol] = v;
            else           outb[(size_t)grow * DD + gcol] = f2bf(v);
        }
    }
}

extern "C" void kernel_launch(void* const* d_in, const int* in_sizes, int n_in,
                              void* d_out, int out_size, void* d_ws, size_t ws_size,
                              hipStream_t stream) {
    const float* x    = (const float*)d_in[0];
    const int*   edge = (const int*)d_in[1];     // [2, E] int32
    const int*   srcp = edge;
    const int*   dstp = edge + EE;
    const float* W1l = (const float*)d_in[2];
    const float* b1  = (const float*)d_in[3];
    const float* W1r = (const float*)d_in[4];
    const float* W2l = (const float*)d_in[5];
    const float* b2  = (const float*)d_in[6];
    const float* W2r = (const float*)d_in[7];
    const float* W3l = (const float*)d_in[8];
    const float* b3  = (const float*)d_in[9];
    const float* W3r = (const float*)d_in[10];
    float* out = (float*)d_out;

    char* ws = (char*)d_ws;
    size_t off = 0;
    auto alloc = [&](size_t bytes) { void* p = ws + off; off += (bytes + 255) & ~(size_t)255; return p; };
    unsigned short* eidx   = (unsigned short*)alloc((size_t)NN * SLOTS * 2);      // 6.4 MB padded slots
    int*            cntpad = (int*)           alloc((size_t)NN * CSTRIDE * 4);    // 3.2 MB line-strided counters
    unsigned short* Bw     = (unsigned short*)alloc((size_t)3 * DD * 256 * 2);
    unsigned short* xb     = (unsigned short*)alloc((size_t)(NN + 1) * DD * 2);   // +1 zero row (sentinel NN)
    unsigned short* h1b    = (unsigned short*)alloc((size_t)(NN + 1) * DD * 2);
    unsigned short* h2b    = (unsigned short*)alloc((size_t)(NN + 1) * DD * 2);

    zero_kernel<<<ZR_GRID, 256, 0, stream>>>(cntpad, eidx);

    const int pb_grid = BKT_BLKS + CVT_BLKS + WCAT_BLKS + ZR_BLKS;
    prepbucket_kernel<<<pb_grid, 256, 0, stream>>>(srcp, dstp, x, W1l, W1r, W2l, W2r, W3l, W3r,
                                                   cntpad, eidx, xb, Bw, h1b, h2b);

    const int layer_grid = (NN + 15) / 16;     // 3125

    // layer 1: xb -> h1b (ReLU)
    layer_kernel<1, 0><<<layer_grid, 256, 0, stream>>>(xb, eidx, cntpad, Bw, b1, nullptr, h1b, NN);
    // layer 2: h1b -> h2b (ReLU)
    layer_kernel<1, 0><<<layer_grid, 256, 0, stream>>>(h1b, eidx, cntpad, Bw + 32768, b2, nullptr, h2b, NN);
    // layer 3: h2b -> out fp32 (no ReLU)
    layer_kernel<0, 1><<<layer_grid, 256, 0, stream>>>(h2b, eidx, cntpad, Bw + 65536, b3, out, nullptr, NN);
}

// Round 6
// 285.272 us; speedup vs baseline: 1.5736x; 1.5736x over previous
//
#include <hip/hip_runtime.h>

#define NN 50000
#define DD 128
#define EE 800000
#define SLOTS 64          // max degree cap (Poisson(16): P(deg>=65) ~ 1e-20/node)
#define CSTRIDE 16        // ints per counter -> one counter per 64B line
#define NSHARD 8          // XCDs; blockIdx % 8 ~ XCD round-robin (perf heuristic only)
#define SHARD_NODES (NN / NSHARD)   // 6250

// merged prep+bucket block ranges (bucket first: it's the long pole)
#define BKT_BLKS  6256    // 782 chunks x 8 shards
#define CVT_BLKS  6250    // NN*DD/4 float4s / 256
#define WCAT_BLKS 384
#define ZR_BLKS   1

// zero pass: cntpad (200000 uint4) + eidx sentinel fill (400000 uint4)
#define ZCNT_U4   (NN * CSTRIDE / 4)
#define ZEIDX_U4  (NN * SLOTS / 8)
#define ZR_GRID   ((ZCNT_U4 + ZEIDX_U4 + 255) / 256)

typedef short bf16x8 __attribute__((ext_vector_type(8)));   // 8 bf16 = 4 VGPRs
typedef float f32x4  __attribute__((ext_vector_type(4)));
typedef unsigned u32x4 __attribute__((ext_vector_type(4))); // asm payload quad (4 VGPRs)

// ---- bf16 helpers (RNE) ----
__device__ __forceinline__ unsigned short f2bf(float f) {
    union { float f; unsigned u; } c; c.f = f;
    unsigned r = c.u + 0x7fffu + ((c.u >> 16) & 1u);
    return (unsigned short)(r >> 16);
}
__device__ __forceinline__ float bflo(unsigned p) { union { unsigned u; float f; } c; c.u = p << 16; return c.f; }
__device__ __forceinline__ float bfhi(unsigned p) { union { unsigned u; float f; } c; c.u = p & 0xffff0000u; return c.f; }
__device__ __forceinline__ unsigned packbf(float a, float b) { return (unsigned)f2bf(a) | ((unsigned)f2bf(b) << 16); }

// generic LDS pointer -> 32-bit LDS byte address (addrspacecast, then ptrtoint)
__device__ __forceinline__ unsigned lds_addr(void* p) {
    return (unsigned)(unsigned long long)(__attribute__((address_space(3))) void*)p;
}

// ---------------- cnt zero + eidx sentinel fill (must precede bucket atomics) ----------------
// eidx prefilled with NN (0xC350) so slots >= deg point at the zero sentinel row: the gather
// then needs NO cap-masking, every batch is safe to load, and addresses don't depend on deg.
__global__ __launch_bounds__(256) void zero_kernel(int* __restrict__ cntpad, unsigned short* __restrict__ eidx) {
    int i = blockIdx.x * 256 + threadIdx.x;     // uint4 index
    if (i < ZCNT_U4) {
        ((uint4*)cntpad)[i] = make_uint4(0, 0, 0, 0);
    } else {
        int j = i - ZCNT_U4;
        if (j < ZEIDX_U4) ((uint4*)eidx)[j] = make_uint4(0xC350C350u, 0xC350C350u, 0xC350C350u, 0xC350C350u);
    }
}

// ---------------- merged prep + padded-slot CSR build (independent parts, one dispatch) ----
// R11 evidence: bucket (~40us) + prep (~25us) merged costs only ~45us (overlapped).
__global__ __launch_bounds__(256) void prepbucket_kernel(const int* __restrict__ src, const int* __restrict__ dst,
                                                         const float* __restrict__ x,
                                                         const float* __restrict__ W1l, const float* __restrict__ W1r,
                                                         const float* __restrict__ W2l, const float* __restrict__ W2r,
                                                         const float* __restrict__ W3l, const float* __restrict__ W3r,
                                                         int* __restrict__ cntpad, unsigned short* __restrict__ eidx,
                                                         unsigned short* __restrict__ xb,
                                                         unsigned short* __restrict__ Bw,
                                                         unsigned short* __restrict__ h1b,
                                                         unsigned short* __restrict__ h2b) {
    const int b = blockIdx.x;
    const int t = threadIdx.x;
    if (b < BKT_BLKS) {
        const int shard = b & (NSHARD - 1);
        const int chunk = b >> 3;
        const int lo = shard * SHARD_NODES;
        const int hi = lo + SHARD_NODES;
        int i = (chunk * 256 + t) * 4;
        if (i + 3 < EE) {
            int4 dv = *(const int4*)(dst + i);
            int4 sv = *(const int4*)(src + i);
            if (dv.x >= lo && dv.x < hi) { int p = atomicAdd(&cntpad[dv.x * CSTRIDE], 1); if (p < SLOTS) eidx[dv.x * SLOTS + p] = (unsigned short)sv.x; }
            if (dv.y >= lo && dv.y < hi) { int p = atomicAdd(&cntpad[dv.y * CSTRIDE], 1); if (p < SLOTS) eidx[dv.y * SLOTS + p] = (unsigned short)sv.y; }
            if (dv.z >= lo && dv.z < hi) { int p = atomicAdd(&cntpad[dv.z * CSTRIDE], 1); if (p < SLOTS) eidx[dv.z * SLOTS + p] = (unsigned short)sv.z; }
            if (dv.w >= lo && dv.w < hi) { int p = atomicAdd(&cntpad[dv.w * CSTRIDE], 1); if (p < SLOTS) eidx[dv.w * SLOTS + p] = (unsigned short)sv.w; }
        } else {
            for (int e = i; e < EE; ++e) {
                int d = dst[e];
                if (d >= lo && d < hi) {
                    int p = atomicAdd(&cntpad[d * CSTRIDE], 1);
                    if (p < SLOTS) eidx[d * SLOTS + p] = (unsigned short)src[e];
                }
            }
        }
    } else if (b < BKT_BLKS + CVT_BLKS) {
        int i = (b - BKT_BLKS) * 256 + t;         // float4 index, exactly NN*DD/4
        float4 v = ((const float4*)x)[i];
        uint2 o;
        o.x = packbf(v.x, v.y);
        o.y = packbf(v.z, v.w);
        ((uint2*)xb)[i] = o;
    } else if (b < BKT_BLKS + CVT_BLKS + WCAT_BLKS) {
        int gid = (b - BKT_BLKS - CVT_BLKS) * 256 + t;   // 0..98303
        int layer = gid >> 15;
        int rem = gid & 32767;
        int c = rem >> 8;
        int k = rem & 255;
        const float* Wl = (layer == 0) ? W1l : (layer == 1) ? W2l : W3l;
        const float* Wr = (layer == 0) ? W1r : (layer == 1) ? W2r : W3r;
        float v = (k < 128) ? Wl[(size_t)c * DD + k] : Wr[(size_t)c * DD + (k - 128)];
        Bw[gid] = f2bf(v);
    } else {
        // zero sentinel row NN of xb/h1b/h2b: 3 rows x 256B = 48 uint4
        if (t < 48) {
            unsigned short* base = (t < 16) ? xb : (t < 32) ? h1b : h2b;
            ((uint4*)(base + (size_t)NN * DD))[t & 15] = make_uint4(0, 0, 0, 0);
        }
    }
}

// ---------------- fused layer: gather 16 nodes -> LDS FIFO -> accumulate -> MFMA dual-GEMM --
// R13-R16 post-mortems: every VGPR-resident gather pipeline was defeated by the compiler
// (demoted / sunk / spilled / spilled-around-asm; R16: VGPR stuck 32, WRITE_SIZE 212 MB).
// R17: the pipeline payload lives in LDS (unspillable) via global_load_lds DMA:
//  * one instruction = 64 lanes x 16B = 4 rows (1 slot per quarter's node), 1 KB -> LDS at
//    wave-uniform base + lane*16 (m104/m173: global src addr IS per-lane; dest is linear).
//  * batch = 4 instrs = 4 slots/node = 4 KB; FIFO = 2 batches/wave = 8 KB; fixed-immediate
//    pipeline: prologue issues b0,b1 (8 outstanding); loop: vmcnt(4) -> asm ds_read_b128 x4
//    -> lgkmcnt(0)+sched_barrier (rule #18) -> issue b+2 into freed slot -> ACCUM.
//  * batches >= 16 clamp to sentinel row (L1-resident broadcast) -> single-exit loop,
//    constant outstanding count, no tail variants.
//  * register demand back to ~R12 level; LDS 4x8KB fifo + sA = 37 KB -> 4 blocks/CU
//    (16 waves/CU), sustained ~128 KB in flight per CU vs R12's bursty ~7 KB average.
template <int RELU, int WRITE_F32>
__global__ __launch_bounds__(256, 4) void layer_kernel(const unsigned short* __restrict__ hb,
                                                       const unsigned short* __restrict__ eidx,
                                                       const int* __restrict__ cntpad,
                                                       const unsigned short* __restrict__ Bw,
                                                       const float* __restrict__ bias,
                                                       float* __restrict__ outf,
                                                       unsigned short* __restrict__ outb, int n) {
    (void)n;
    __shared__ __align__(16) unsigned char fifo[4][8192];   // [wave][2 batches x 4 slots x 1KB]
    __shared__ __align__(16) unsigned short sA[16][136];
    const int tid  = threadIdx.x;
    const int w    = tid >> 6;          // wave 0..3
    const int lane = tid & 63;
    const int row0 = blockIdx.x * 16;
    const int sub  = lane >> 4;         // quarter 0..3 -> node within wave
    const int q    = lane & 15;         // 16B slot within the 256B row
    const int qs   = q * 8;             // short offset of this lane's 16B chunk

    // ---- Phase A: 4 nodes per wave, one per quarter; lane q owns channels 8q..8q+7 ----
    const int node = row0 + (w << 2) + sub;
    const int deg  = cntpad[node * CSTRIDE];
    // lane's 4 slot indices (slots q*4..q*4+3 of its node); sentinel-padded past deg
    uint2 mi = *(const uint2*)(eidx + (size_t)node * SLOTS + q * 4);

    const int cap = deg < SLOTS ? deg : SLOTS;
    int cmax = cap;
    cmax = max(cmax, __shfl_xor(cmax, 16));
    cmax = max(cmax, __shfl_xor(cmax, 32));
    const int nb = (cmax + 3) >> 2;     // batches of 4 slots, wave-uniform, 0..16

    float a0 = 0.f, a1 = 0.f, a2 = 0.f, a3 = 0.f, a4 = 0.f, a5 = 0.f, a6 = 0.f, a7 = 0.f;

    const unsigned lrd = lds_addr(&fifo[w][0]) + (unsigned)(lane * 16);

// batch BB: source lane (sub<<4)|(BB&15) holds slots 4BB..4BB+3; BB>=16 -> sentinel row.
// 4 DMA instrs: instr k loads row i_k (one per quarter) into fifo slot (BB&1), chunk k.
#define ISSUE(BB)                                                                           \
    {                                                                                       \
        const int bb_ = (BB);                                                               \
        const int sl_ = (sub << 4) | (bb_ & 15);                                            \
        unsigned p0_ = (unsigned)__shfl((int)mi.x, sl_);                                    \
        unsigned p1_ = (unsigned)__shfl((int)mi.y, sl_);                                    \
        p0_ = (bb_ < 16) ? p0_ : 0xC350C350u;                                               \
        p1_ = (bb_ < 16) ? p1_ : 0xC350C350u;                                               \
        unsigned char* d_ = &fifo[w][(unsigned)((bb_ & 1) << 12)];                          \
        __builtin_amdgcn_global_load_lds(                                                   \
            (const __attribute__((address_space(1))) void*)(hb + (size_t)(p0_ & 0xffffu) * DD + qs), \
            (__attribute__((address_space(3))) void*)(d_ + 0), 16, 0, 0);                   \
        __builtin_amdgcn_global_load_lds(                                                   \
            (const __attribute__((address_space(1))) void*)(hb + (size_t)(p0_ >> 16) * DD + qs),     \
            (__attribute__((address_space(3))) void*)(d_ + 1024), 16, 0, 0);                \
        __builtin_amdgcn_global_load_lds(                                                   \
            (const __attribute__((address_space(1))) void*)(hb + (size_t)(p1_ & 0xffffu) * DD + qs), \
            (__attribute__((address_space(3))) void*)(d_ + 2048), 16, 0, 0);                \
        __builtin_amdgcn_global_load_lds(                                                   \
            (const __attribute__((address_space(1))) void*)(hb + (size_t)(p1_ >> 16) * DD + qs),     \
            (__attribute__((address_space(3))) void*)(d_ + 3072), 16, 0, 0);                \
    }

    __builtin_amdgcn_sched_barrier(0);
    ISSUE(0);                           // prologue: 2 batches = 8 loads in flight
    ISSUE(1);
#pragma unroll 1
    for (int b = 0; b < nb; ++b) {
        asm volatile("s_waitcnt vmcnt(4)" ::: "memory");    // batch b's 4 DMAs landed
        __builtin_amdgcn_sched_barrier(0);
        const unsigned ra = lrd + (unsigned)((b & 1) << 12);
        u32x4 V0, V1, V2, V3;
        asm volatile("ds_read_b128 %0, %1 offset:0"    : "=v"(V0) : "v"(ra) : "memory");
        asm volatile("ds_read_b128 %0, %1 offset:1024" : "=v"(V1) : "v"(ra) : "memory");
        asm volatile("ds_read_b128 %0, %1 offset:2048" : "=v"(V2) : "v"(ra) : "memory");
        asm volatile("ds_read_b128 %0, %1 offset:3072" : "=v"(V3) : "v"(ra) : "memory");
        asm volatile("s_waitcnt lgkmcnt(0)" ::: "memory");
        __builtin_amdgcn_sched_barrier(0);                  // rule #18: pin ACCUM below wait
        ISSUE(b + 2);                                       // refill freed slot -> 8 in flight
        a0 += (bflo(V0[0]) + bflo(V1[0])) + (bflo(V2[0]) + bflo(V3[0]));
        a1 += (bfhi(V0[0]) + bfhi(V1[0])) + (bfhi(V2[0]) + bfhi(V3[0]));
        a2 += (bflo(V0[1]) + bflo(V1[1])) + (bflo(V2[1]) + bflo(V3[1]));
        a3 += (bfhi(V0[1]) + bfhi(V1[1])) + (bfhi(V2[1]) + bfhi(V3[1]));
        a4 += (bflo(V0[2]) + bflo(V1[2])) + (bflo(V2[2]) + bflo(V3[2]));
        a5 += (bfhi(V0[2]) + bfhi(V1[2])) + (bfhi(V2[2]) + bfhi(V3[2]));
        a6 += (bflo(V0[3]) + bflo(V1[3])) + (bflo(V2[3]) + bflo(V3[3]));
        a7 += (bfhi(V0[3]) + bfhi(V1[3])) + (bfhi(V2[3]) + bfhi(V3[3]));
    }
#undef ISSUE

    {
        const float inv = (deg > 0) ? (1.0f / (float)deg) : 0.f;
        uint4 o;
        o.x = packbf(a0 * inv, a1 * inv);
        o.y = packbf(a2 * inv, a3 * inv);
        o.z = packbf(a4 * inv, a5 * inv);
        o.w = packbf(a6 * inv, a7 * inv);
        *(uint4*)&sA[(w << 2) | sub][q * 8] = o;
    }
    __syncthreads();    // also drains leftover sentinel DMAs (they only touch this wave's fifo)

    // ---- Phase B: MFMA dual-GEMM. All waves share the 16 rows; wave w owns 32 cols ----
    const int m    = lane & 15;
    const int quad = lane >> 4;
    const int arow = row0 + m;

    f32x4 acc[2];
    acc[0] = (f32x4){0.f, 0.f, 0.f, 0.f};
    acc[1] = (f32x4){0.f, 0.f, 0.f, 0.f};

    const unsigned short* aptr = hb + (size_t)arow * DD + quad * 8;
#pragma unroll
    for (int ph = 0; ph < 2; ++ph) {
#pragma unroll
        for (int ks = 0; ks < 4; ++ks) {
            bf16x8 af;
            if (ph == 0) {
                af = *(const bf16x8*)&sA[m][ks * 32 + quad * 8];
            } else {
                af = *(const bf16x8*)(aptr + ks * 32);
            }
            const int koff = ph * 128 + ks * 32 + quad * 8;
#pragma unroll
            for (int ct = 0; ct < 2; ++ct) {
                const int c = w * 32 + ct * 16 + m;
                bf16x8 bfv = *(const bf16x8*)(Bw + (size_t)c * 256 + koff);
                acc[ct] = __builtin_amdgcn_mfma_f32_16x16x32_bf16(af, bfv, acc[ct], 0, 0, 0);
            }
        }
    }

#pragma unroll
    for (int ct = 0; ct < 2; ++ct) {
        const int gcol = w * 32 + ct * 16 + m;
        const float bv = bias[gcol];
#pragma unroll
        for (int r = 0; r < 4; ++r) {
            const int grow = row0 + quad * 4 + r;
            float v = acc[ct][r] + bv;
            if (RELU) v = fmaxf(v, 0.f);
            if (WRITE_F32) outf[(size_t)grow * DD + gcol] = v;
            else           outb[(size_t)grow * DD + gcol] = f2bf(v);
        }
    }
}

extern "C" void kernel_launch(void* const* d_in, const int* in_sizes, int n_in,
                              void* d_out, int out_size, void* d_ws, size_t ws_size,
                              hipStream_t stream) {
    const float* x    = (const float*)d_in[0];
    const int*   edge = (const int*)d_in[1];     // [2, E] int32
    const int*   srcp = edge;
    const int*   dstp = edge + EE;
    const float* W1l = (const float*)d_in[2];
    const float* b1  = (const float*)d_in[3];
    const float* W1r = (const float*)d_in[4];
    const float* W2l = (const float*)d_in[5];
    const float* b2  = (const float*)d_in[6];
    const float* W2r = (const float*)d_in[7];
    const float* W3l = (const float*)d_in[8];
    const float* b3  = (const float*)d_in[9];
    const float* W3r = (const float*)d_in[10];
    float* out = (float*)d_out;

    char* ws = (char*)d_ws;
    size_t off = 0;
    auto alloc = [&](size_t bytes) { void* p = ws + off; off += (bytes + 255) & ~(size_t)255; return p; };
    unsigned short* eidx   = (unsigned short*)alloc((size_t)NN * SLOTS * 2);      // 6.4 MB padded slots
    int*            cntpad = (int*)           alloc((size_t)NN * CSTRIDE * 4);    // 3.2 MB line-strided counters
    unsigned short* Bw     = (unsigned short*)alloc((size_t)3 * DD * 256 * 2);
    unsigned short* xb     = (unsigned short*)alloc((size_t)(NN + 1) * DD * 2);   // +1 zero row (sentinel NN)
    unsigned short* h1b    = (unsigned short*)alloc((size_t)(NN + 1) * DD * 2);
    unsigned short* h2b    = (unsigned short*)alloc((size_t)(NN + 1) * DD * 2);

    zero_kernel<<<ZR_GRID, 256, 0, stream>>>(cntpad, eidx);

    const int pb_grid = BKT_BLKS + CVT_BLKS + WCAT_BLKS + ZR_BLKS;
    prepbucket_kernel<<<pb_grid, 256, 0, stream>>>(srcp, dstp, x, W1l, W1r, W2l, W2r, W3l, W3r,
                                                   cntpad, eidx, xb, Bw, h1b, h2b);

    const int layer_grid = (NN + 15) / 16;     // 3125

    // layer 1: xb -> h1b (ReLU)
    layer_kernel<1, 0><<<layer_grid, 256, 0, stream>>>(xb, eidx, cntpad, Bw, b1, nullptr, h1b, NN);
    // layer 2: h1b -> h2b (ReLU)
    layer_kernel<1, 0><<<layer_grid, 256, 0, stream>>>(h1b, eidx, cntpad, Bw + 32768, b2, nullptr, h2b, NN);
    // layer 3: h2b -> out fp32 (no ReLU)
    layer_kernel<0, 1><<<layer_grid, 256, 0, stream>>>(h2b, eidx, cntpad, Bw + 65536, b3, out, nullptr, NN);
}

// Round 7
// 283.482 us; speedup vs baseline: 1.5835x; 1.0063x over previous
//
#include <hip/hip_runtime.h>

#define NN 50000
#define DD 128
#define EE 800000
#define SLOTS 64          // max degree cap (Poisson(16): P(deg>=65) ~ 1e-20/node)
#define CSTRIDE 16        // ints per counter -> one counter per 64B line
#define NSHARD 8          // XCDs; blockIdx % 8 ~ XCD round-robin (perf heuristic only)
#define SHARD_NODES (NN / NSHARD)   // 6250

// merged prep+bucket block ranges (bucket first: it's the long pole)
#define BKT_BLKS  6256    // 782 chunks x 8 shards
#define CVT_BLKS  6250    // NN*DD/4 float4s / 256
#define WCAT_BLKS 384
#define ZR_BLKS   1

typedef short bf16x8 __attribute__((ext_vector_type(8)));   // 8 bf16 = 4 VGPRs
typedef float f32x4  __attribute__((ext_vector_type(4)));
typedef unsigned u32x4 __attribute__((ext_vector_type(4))); // asm payload quad (4 VGPRs)

// ---- bf16 helpers (RNE) ----
__device__ __forceinline__ unsigned short f2bf(float f) {
    union { float f; unsigned u; } c; c.f = f;
    unsigned r = c.u + 0x7fffu + ((c.u >> 16) & 1u);
    return (unsigned short)(r >> 16);
}
__device__ __forceinline__ float bflo(unsigned p) { union { unsigned u; float f; } c; c.u = p << 16; return c.f; }
__device__ __forceinline__ float bfhi(unsigned p) { union { unsigned u; float f; } c; c.u = p & 0xffff0000u; return c.f; }
__device__ __forceinline__ unsigned packbf(float a, float b) { return (unsigned)f2bf(a) | ((unsigned)f2bf(b) << 16); }

// generic LDS pointer -> 32-bit LDS byte address (addrspacecast, then ptrtoint)
__device__ __forceinline__ unsigned lds_addr(void* p) {
    return (unsigned)(unsigned long long)(__attribute__((address_space(3))) void*)p;
}

// ---------------- merged prep + padded-slot CSR build (independent parts, one dispatch) ----
// R11 evidence: bucket (~40us) + prep (~25us) merged costs only ~45us (overlapped).
// R18: cntpad now zeroed by hipMemsetAsync (blitter); eidx needs NO sentinel prefill because
// the layer gather cap-masks slot indices in-register (slots >= cap -> sentinel row NN).
__global__ __launch_bounds__(256) void prepbucket_kernel(const int* __restrict__ src, const int* __restrict__ dst,
                                                         const float* __restrict__ x,
                                                         const float* __restrict__ W1l, const float* __restrict__ W1r,
                                                         const float* __restrict__ W2l, const float* __restrict__ W2r,
                                                         const float* __restrict__ W3l, const float* __restrict__ W3r,
                                                         int* __restrict__ cntpad, unsigned short* __restrict__ eidx,
                                                         unsigned short* __restrict__ xb,
                                                         unsigned short* __restrict__ Bw,
                                                         unsigned short* __restrict__ h1b,
                                                         unsigned short* __restrict__ h2b) {
    const int b = blockIdx.x;
    const int t = threadIdx.x;
    if (b < BKT_BLKS) {
        const int shard = b & (NSHARD - 1);
        const int chunk = b >> 3;
        const int lo = shard * SHARD_NODES;
        const int hi = lo + SHARD_NODES;
        int i = (chunk * 256 + t) * 4;
        if (i + 3 < EE) {
            int4 dv = *(const int4*)(dst + i);
            int4 sv = *(const int4*)(src + i);
            if (dv.x >= lo && dv.x < hi) { int p = atomicAdd(&cntpad[dv.x * CSTRIDE], 1); if (p < SLOTS) eidx[dv.x * SLOTS + p] = (unsigned short)sv.x; }
            if (dv.y >= lo && dv.y < hi) { int p = atomicAdd(&cntpad[dv.y * CSTRIDE], 1); if (p < SLOTS) eidx[dv.y * SLOTS + p] = (unsigned short)sv.y; }
            if (dv.z >= lo && dv.z < hi) { int p = atomicAdd(&cntpad[dv.z * CSTRIDE], 1); if (p < SLOTS) eidx[dv.z * SLOTS + p] = (unsigned short)sv.z; }
            if (dv.w >= lo && dv.w < hi) { int p = atomicAdd(&cntpad[dv.w * CSTRIDE], 1); if (p < SLOTS) eidx[dv.w * SLOTS + p] = (unsigned short)sv.w; }
        } else {
            for (int e = i; e < EE; ++e) {
                int d = dst[e];
                if (d >= lo && d < hi) {
                    int p = atomicAdd(&cntpad[d * CSTRIDE], 1);
                    if (p < SLOTS) eidx[d * SLOTS + p] = (unsigned short)src[e];
                }
            }
        }
    } else if (b < BKT_BLKS + CVT_BLKS) {
        int i = (b - BKT_BLKS) * 256 + t;         // float4 index, exactly NN*DD/4
        float4 v = ((const float4*)x)[i];
        uint2 o;
        o.x = packbf(v.x, v.y);
        o.y = packbf(v.z, v.w);
        ((uint2*)xb)[i] = o;
    } else if (b < BKT_BLKS + CVT_BLKS + WCAT_BLKS) {
        int gid = (b - BKT_BLKS - CVT_BLKS) * 256 + t;   // 0..98303
        int layer = gid >> 15;
        int rem = gid & 32767;
        int c = rem >> 8;
        int k = rem & 255;
        const float* Wl = (layer == 0) ? W1l : (layer == 1) ? W2l : W3l;
        const float* Wr = (layer == 0) ? W1r : (layer == 1) ? W2r : W3r;
        float v = (k < 128) ? Wl[(size_t)c * DD + k] : Wr[(size_t)c * DD + (k - 128)];
        Bw[gid] = f2bf(v);
    } else {
        // zero sentinel row NN of xb/h1b/h2b: 3 rows x 256B = 48 uint4
        if (t < 48) {
            unsigned short* base = (t < 16) ? xb : (t < 32) ? h1b : h2b;
            ((uint4*)(base + (size_t)NN * DD))[t & 15] = make_uint4(0, 0, 0, 0);
        }
    }
}

// ---------------- fused layer: gather 16 nodes -> LDS FIFO -> accumulate -> MFMA dual-GEMM --
// R17 post-mortem: pipeline was structurally intact (VGPR 52, no spill) but EVERY asm block
// carried a "memory" clobber -> LLVM's waitcnt pass conservatively drains vmcnt(0) before
// memory-clobbered asm -> depth collapsed to 0 -> 54us == R12's 53us (same effective schedule).
// R18, two levers:
//  * TRUE depth-2: no "memory" clobbers anywhere in the loop. Ordering = volatile-asm program
//    order (LLVM preserves relative order of volatile asm) + sched_barrier(0) seams (rule #18:
//    pin dependent VALU below the hand-placed lgkmcnt). fifo is touched ONLY by the DMA builtin
//    and opaque asm reads -> no compiler alias edge -> no auto-drain. The __syncthreads after
//    Phase A still drains the leftover 2 sentinel batches (compiler-known DMAs).
//  * L1-bypass probe: DMA aux=1 (SC0). If the ~2 TB/s plateau is per-CU L1 miss-tracking
//    (need ~18 lines in flight at 900cy; plausible MSHR cap), bypass shifts tracking to L2.
//  * cap-mask in ISSUE (slot < cap ? idx : sentinel NN) -> eidx prefill no longer needed.
template <int RELU, int WRITE_F32>
__global__ __launch_bounds__(256, 4) void layer_kernel(const unsigned short* __restrict__ hb,
                                                       const unsigned short* __restrict__ eidx,
                                                       const int* __restrict__ cntpad,
                                                       const unsigned short* __restrict__ Bw,
                                                       const float* __restrict__ bias,
                                                       float* __restrict__ outf,
                                                       unsigned short* __restrict__ outb, int n) {
    (void)n;
    __shared__ __align__(16) unsigned char fifo[4][8192];   // [wave][2 batches x 4 slots x 1KB]
    __shared__ __align__(16) unsigned short sA[16][136];
    const int tid  = threadIdx.x;
    const int w    = tid >> 6;          // wave 0..3
    const int lane = tid & 63;
    const int row0 = blockIdx.x * 16;
    const int sub  = lane >> 4;         // quarter 0..3 -> node within wave
    const int q    = lane & 15;         // 16B slot within the 256B row
    const int qs   = q * 8;             // short offset of this lane's 16B chunk

    // ---- Phase A: 4 nodes per wave, one per quarter; lane q owns channels 8q..8q+7 ----
    const int node = row0 + (w << 2) + sub;
    const int deg  = cntpad[node * CSTRIDE];
    // lane's 4 slot indices (slots q*4..q*4+3 of its node); garbage past deg (masked below)
    uint2 mi = *(const uint2*)(eidx + (size_t)node * SLOTS + q * 4);

    const int cap = deg < SLOTS ? deg : SLOTS;   // quarter-uniform (all lanes of sub share node)
    int cmax = cap;
    cmax = max(cmax, __shfl_xor(cmax, 16));
    cmax = max(cmax, __shfl_xor(cmax, 32));
    const int nb = (cmax + 3) >> 2;     // batches of 4 slots, wave-uniform, 0..16

    float a0 = 0.f, a1 = 0.f, a2 = 0.f, a3 = 0.f, a4 = 0.f, a5 = 0.f, a6 = 0.f, a7 = 0.f;

    const unsigned lrd = lds_addr(&fifo[w][0]) + (unsigned)(lane * 16);

// batch BB: source lane (sub<<4)|(BB&15) holds slots 4BB..4BB+3 of this quarter's node;
// slots >= cap (incl. whole batches >= 16) masked to sentinel row NN (zeros, L1-resident).
// aux=1 (SC0): L1 bypass on the gather DMAs.
#define ISSUE(BB)                                                                           \
    {                                                                                       \
        const int bb_ = (BB);                                                               \
        const int sl_ = (sub << 4) | (bb_ & 15);                                            \
        unsigned p0_ = (unsigned)__shfl((int)mi.x, sl_);                                    \
        unsigned p1_ = (unsigned)__shfl((int)mi.y, sl_);                                    \
        const int s0_ = bb_ << 2;                                                           \
        unsigned r0_ = (s0_     < cap) ? (p0_ & 0xffffu) : (unsigned)NN;                    \
        unsigned r1_ = (s0_ + 1 < cap) ? (p0_ >> 16)     : (unsigned)NN;                    \
        unsigned r2_ = (s0_ + 2 < cap) ? (p1_ & 0xffffu) : (unsigned)NN;                    \
        unsigned r3_ = (s0_ + 3 < cap) ? (p1_ >> 16)     : (unsigned)NN;                    \
        unsigned char* d_ = &fifo[w][(unsigned)((bb_ & 1) << 12)];                          \
        __builtin_amdgcn_global_load_lds(                                                   \
            (const __attribute__((address_space(1))) void*)(hb + (size_t)r0_ * DD + qs),    \
            (__attribute__((address_space(3))) void*)(d_ + 0), 16, 0, 1);                   \
        __builtin_amdgcn_global_load_lds(                                                   \
            (const __attribute__((address_space(1))) void*)(hb + (size_t)r1_ * DD + qs),    \
            (__attribute__((address_space(3))) void*)(d_ + 1024), 16, 0, 1);                \
        __builtin_amdgcn_global_load_lds(                                                   \
            (const __attribute__((address_space(1))) void*)(hb + (size_t)r2_ * DD + qs),    \
            (__attribute__((address_space(3))) void*)(d_ + 2048), 16, 0, 1);                \
        __builtin_amdgcn_global_load_lds(                                                   \
            (const __attribute__((address_space(1))) void*)(hb + (size_t)r3_ * DD + qs),    \
            (__attribute__((address_space(3))) void*)(d_ + 3072), 16, 0, 1);                \
    }

    __builtin_amdgcn_sched_barrier(0);
    ISSUE(0);                           // prologue: 2 batches = 8 DMAs in flight
    ISSUE(1);
    __builtin_amdgcn_sched_barrier(0);
#pragma unroll 1
    for (int b = 0; b < nb; ++b) {
        asm volatile("s_waitcnt vmcnt(4)");                 // batch b's 4 DMAs landed (no clobber!)
        __builtin_amdgcn_sched_barrier(0);
        const unsigned ra = lrd + (unsigned)((b & 1) << 12);
        u32x4 V0, V1, V2, V3;
        asm volatile("ds_read_b128 %0, %1 offset:0"    : "=v"(V0) : "v"(ra));
        asm volatile("ds_read_b128 %0, %1 offset:1024" : "=v"(V1) : "v"(ra));
        asm volatile("ds_read_b128 %0, %1 offset:2048" : "=v"(V2) : "v"(ra));
        asm volatile("ds_read_b128 %0, %1 offset:3072" : "=v"(V3) : "v"(ra));
        asm volatile("s_waitcnt lgkmcnt(0)");
        __builtin_amdgcn_sched_barrier(0);                  // rule #18: pin consumers below wait
        ISSUE(b + 2);                                       // refill freed slot -> 8 in flight
        a0 += (bflo(V0[0]) + bflo(V1[0])) + (bflo(V2[0]) + bflo(V3[0]));
        a1 += (bfhi(V0[0]) + bfhi(V1[0])) + (bfhi(V2[0]) + bfhi(V3[0]));
        a2 += (bflo(V0[1]) + bflo(V1[1])) + (bflo(V2[1]) + bflo(V3[1]));
        a3 += (bfhi(V0[1]) + bfhi(V1[1])) + (bfhi(V2[1]) + bfhi(V3[1]));
        a4 += (bflo(V0[2]) + bflo(V1[2])) + (bflo(V2[2]) + bflo(V3[2]));
        a5 += (bfhi(V0[2]) + bfhi(V1[2])) + (bfhi(V2[2]) + bfhi(V3[2]));
        a6 += (bflo(V0[3]) + bflo(V1[3])) + (bflo(V2[3]) + bflo(V3[3]));
        a7 += (bfhi(V0[3]) + bfhi(V1[3])) + (bfhi(V2[3]) + bfhi(V3[3]));
    }
#undef ISSUE

    {
        const float inv = (deg > 0) ? (1.0f / (float)deg) : 0.f;
        uint4 o;
        o.x = packbf(a0 * inv, a1 * inv);
        o.y = packbf(a2 * inv, a3 * inv);
        o.z = packbf(a4 * inv, a5 * inv);
        o.w = packbf(a6 * inv, a7 * inv);
        *(uint4*)&sA[(w << 2) | sub][q * 8] = o;
    }
    __syncthreads();    // drains leftover sentinel DMAs (compiler-known) + publishes sA

    // ---- Phase B: MFMA dual-GEMM. All waves share the 16 rows; wave w owns 32 cols ----
    const int m    = lane & 15;
    const int quad = lane >> 4;
    const int arow = row0 + m;

    f32x4 acc[2];
    acc[0] = (f32x4){0.f, 0.f, 0.f, 0.f};
    acc[1] = (f32x4){0.f, 0.f, 0.f, 0.f};

    const unsigned short* aptr = hb + (size_t)arow * DD + quad * 8;
#pragma unroll
    for (int ph = 0; ph < 2; ++ph) {
#pragma unroll
        for (int ks = 0; ks < 4; ++ks) {
            bf16x8 af;
            if (ph == 0) {
                af = *(const bf16x8*)&sA[m][ks * 32 + quad * 8];
            } else {
                af = *(const bf16x8*)(aptr + ks * 32);
            }
            const int koff = ph * 128 + ks * 32 + quad * 8;
#pragma unroll
            for (int ct = 0; ct < 2; ++ct) {
                const int c = w * 32 + ct * 16 + m;
                bf16x8 bfv = *(const bf16x8*)(Bw + (size_t)c * 256 + koff);
                acc[ct] = __builtin_amdgcn_mfma_f32_16x16x32_bf16(af, bfv, acc[ct], 0, 0, 0);
            }
        }
    }

#pragma unroll
    for (int ct = 0; ct < 2; ++ct) {
        const int gcol = w * 32 + ct * 16 + m;
        const float bv = bias[gcol];
#pragma unroll
        for (int r = 0; r < 4; ++r) {
            const int grow = row0 + quad * 4 + r;
            float v = acc[ct][r] + bv;
            if (RELU) v = fmaxf(v, 0.f);
            if (WRITE_F32) outf[(size_t)grow * DD + gcol] = v;
            else           outb[(size_t)grow * DD + gcol] = f2bf(v);
        }
    }
}

extern "C" void kernel_launch(void* const* d_in, const int* in_sizes, int n_in,
                              void* d_out, int out_size, void* d_ws, size_t ws_size,
                              hipStream_t stream) {
    const float* x    = (const float*)d_in[0];
    const int*   edge = (const int*)d_in[1];     // [2, E] int32
    const int*   srcp = edge;
    const int*   dstp = edge + EE;
    const float* W1l = (const float*)d_in[2];
    const float* b1  = (const float*)d_in[3];
    const float* W1r = (const float*)d_in[4];
    const float* W2l = (const float*)d_in[5];
    const float* b2  = (const float*)d_in[6];
    const float* W2r = (const float*)d_in[7];
    const float* W3l = (const float*)d_in[8];
    const float* b3  = (const float*)d_in[9];
    const float* W3r = (const float*)d_in[10];
    float* out = (float*)d_out;

    char* ws = (char*)d_ws;
    size_t off = 0;
    auto alloc = [&](size_t bytes) { void* p = ws + off; off += (bytes + 255) & ~(size_t)255; return p; };
    unsigned short* eidx   = (unsigned short*)alloc((size_t)NN * SLOTS * 2);      // 6.4 MB padded slots
    int*            cntpad = (int*)           alloc((size_t)NN * CSTRIDE * 4);    // 3.2 MB line-strided counters
    unsigned short* Bw     = (unsigned short*)alloc((size_t)3 * DD * 256 * 2);
    unsigned short* xb     = (unsigned short*)alloc((size_t)(NN + 1) * DD * 2);   // +1 zero row (sentinel NN)
    unsigned short* h1b    = (unsigned short*)alloc((size_t)(NN + 1) * DD * 2);
    unsigned short* h2b    = (unsigned short*)alloc((size_t)(NN + 1) * DD * 2);

    // cnt zero via blitter (graph-capturable); eidx needs no prefill (cap-masked gather)
    hipMemsetAsync(cntpad, 0, (size_t)NN * CSTRIDE * 4, stream);

    const int pb_grid = BKT_BLKS + CVT_BLKS + WCAT_BLKS + ZR_BLKS;
    prepbucket_kernel<<<pb_grid, 256, 0, stream>>>(srcp, dstp, x, W1l, W1r, W2l, W2r, W3l, W3r,
                                                   cntpad, eidx, xb, Bw, h1b, h2b);

    const int layer_grid = (NN + 15) / 16;     // 3125

    // layer 1: xb -> h1b (ReLU)
    layer_kernel<1, 0><<<layer_grid, 256, 0, stream>>>(xb, eidx, cntpad, Bw, b1, nullptr, h1b, NN);
    // layer 2: h1b -> h2b (ReLU)
    layer_kernel<1, 0><<<layer_grid, 256, 0, stream>>>(h1b, eidx, cntpad, Bw + 32768, b2, nullptr, h2b, NN);
    // layer 3: h2b -> out fp32 (no ReLU)
    layer_kernel<0, 1><<<layer_grid, 256, 0, stream>>>(h2b, eidx, cntpad, Bw + 65536, b3, out, nullptr, NN);
}